// Round 9
// baseline (71.637 us; speedup 1.0000x reference)
//
#include <hip/hip_runtime.h>
#include <hip/hip_bf16.h>
#include <stdint.h>

typedef __attribute__((ext_vector_type(8))) short bf16x8;
typedef __attribute__((ext_vector_type(4))) float f32x4;

#define DIN 1024
#define NROWS 8192

__device__ __forceinline__ unsigned short f2bf(float f) {
    union { float f; unsigned u; } v; v.f = f;
    unsigned r = v.u + 0x7FFFu + ((v.u >> 16) & 1u);  // RNE
    return (unsigned short)(r >> 16);
}

// old 4-chunk/64B swizzle (Whab/Whag only — mt staging uses BK=32 slices)
__device__ __forceinline__ int fswz(int r) { return (r ^ (r >> 2)) & 3; }

// new 8-chunk/128B swizzle for Mt and gABh (BK=64 GEMM operands):
// byte offset of bf16 element (R, c) in a row-major [*,1024] array where within each
// 128B group the 16B chunks are permuted by chunk ^= (R & 7)
__device__ __forceinline__ size_t swz8_byte(int R, int c) {
    return ((size_t)R * DIN + (size_t)(c & ~63)) * 2
         + (size_t)(((((c >> 3) & 7) ^ (R & 7)) << 4))
         + (size_t)((c & 7) * 2);
}

__device__ __forceinline__ void gload_lds16(const void* g, void* l) {
    __builtin_amdgcn_global_load_lds(
        (const __attribute__((address_space(1))) unsigned*)g,
        (__attribute__((address_space(3))) unsigned*)l, 16, 0, 0);
}

// ---- Kernel A: vab/vag/c + cast Wab,Wag -> bf16 (old 64B swizzle, feeds mt) ----
__global__ __launch_bounds__(256) void prep_kernel(const float* __restrict__ Wab,
                                                   const float* __restrict__ Wag,
                                                   const float* __restrict__ bab,
                                                   const float* __restrict__ bag,
                                                   float* __restrict__ ws_f,
                                                   unsigned short* __restrict__ Whab,
                                                   unsigned short* __restrict__ Whag) {
    int b = blockIdx.x;
    int wave = threadIdx.x >> 6, lane = threadIdx.x & 63;
    if (b == 256) {
        if (wave == 0) {
            float acc = 0.f;
            for (int j = lane; j < DIN; j += 64) acc += bab[j] * bag[j];
            for (int off = 32; off; off >>= 1) acc += __shfl_xor(acc, off);
            if (lane == 0) ws_f[2048] = acc;
        }
        return;
    }
    int r = b * 4 + wave;
    int fr = fswz(r);
    {
        const float* wrow = Wab + (size_t)r * DIN;
        char* hrow = (char*)Whab + (size_t)r * DIN * 2;
        float acc = 0.f;
#pragma unroll
        for (int it = 0; it < 4; ++it) {
            int col = it * 256 + lane * 4;
            float4 w = *reinterpret_cast<const float4*>(wrow + col);
            float4 bv = *reinterpret_cast<const float4*>(bag + col);
            acc += w.x * bv.x + w.y * bv.y + w.z * bv.z + w.w * bv.w;
            ushort4 h; h.x = f2bf(w.x); h.y = f2bf(w.y); h.z = f2bf(w.z); h.w = f2bf(w.w);
            *reinterpret_cast<ushort4*>(hrow + (col & ~31) * 2 + ((((col >> 3) & 3) ^ fr) << 4) + (col & 7) * 2) = h;
        }
        for (int off = 32; off; off >>= 1) acc += __shfl_xor(acc, off);
        if (lane == 0) ws_f[r] = acc;          // vab
    }
    {
        const float* wrow = Wag + (size_t)r * DIN;
        char* hrow = (char*)Whag + (size_t)r * DIN * 2;
        float acc = 0.f;
#pragma unroll
        for (int it = 0; it < 4; ++it) {
            int col = it * 256 + lane * 4;
            float4 w = *reinterpret_cast<const float4*>(wrow + col);
            float4 bv = *reinterpret_cast<const float4*>(bab + col);
            acc += w.x * bv.x + w.y * bv.y + w.z * bv.z + w.w * bv.w;
            ushort4 h; h.x = f2bf(w.x); h.y = f2bf(w.y); h.z = f2bf(w.z); h.w = f2bf(w.w);
            *reinterpret_cast<ushort4*>(hrow + (col & ~31) * 2 + ((((col >> 3) & 3) ^ fr) << 4) + (col & 7) * 2) = h;
        }
        for (int off = 32; off; off >>= 1) acc += __shfl_xor(acc, off);
        if (lane == 0) ws_f[1024 + r] = acc;   // vag
    }
}

// ---- Kernel B: Mt[l,k] = Wag[l,:].Wab[k,:]; reads old-swizzle Wh*, writes Mt in NEW 8-chunk swizzle ----
__global__ __launch_bounds__(512) void mt_kernel(const unsigned short* __restrict__ Whag,
                                                 const unsigned short* __restrict__ Whab,
                                                 unsigned short* __restrict__ Mt) {
    __shared__ unsigned short sm[2][2][2][2048];   // [grp][buf][op][64*32] = 32 KB
    int tid = threadIdx.x;
    int wave = tid >> 6, grp = wave >> 2, w4 = wave & 3;
    int lane = tid & 63, kg = lane >> 4, cl = lane & 15;
    int wr = w4 >> 1, wc = w4 & 1;
    int br = blockIdx.x >> 4, bc = blockIdx.x & 15;
    int u = tid & 255, urow = u >> 2, uchunk = u & 3;

    const char* Abase = (const char*)Whag + ((size_t)(br * 64 + urow) * DIN + grp * 512) * 2 + uchunk * 16;
    const char* Bbase = (const char*)Whab + ((size_t)(bc * 64 + urow) * DIN + grp * 512) * 2 + uchunk * 16;

    int offA[2], offB[2];
#pragma unroll
    for (int m = 0; m < 2; ++m) { int row = wr * 32 + m * 16 + cl; offA[m] = row * 32 + ((kg ^ fswz(row)) << 3); }
#pragma unroll
    for (int n = 0; n < 2; ++n) { int row = wc * 32 + n * 16 + cl; offB[n] = row * 32 + ((kg ^ fswz(row)) << 3); }

    f32x4 acc[2][2] = {};
    gload_lds16(Abase, &sm[grp][0][0][u * 8]);
    gload_lds16(Bbase, &sm[grp][0][1][u * 8]);
    for (int t = 0; t < 16; ++t) {
        int p = t & 1;
        __syncthreads();
        if (t < 15) {
            gload_lds16(Abase + (t + 1) * 64, &sm[grp][p ^ 1][0][u * 8]);
            gload_lds16(Bbase + (t + 1) * 64, &sm[grp][p ^ 1][1][u * 8]);
        }
        bf16x8 af[2], bfr[2];
#pragma unroll
        for (int m = 0; m < 2; ++m) af[m] = *reinterpret_cast<const bf16x8*>(&sm[grp][p][0][offA[m]]);
#pragma unroll
        for (int n = 0; n < 2; ++n) bfr[n] = *reinterpret_cast<const bf16x8*>(&sm[grp][p][1][offB[n]]);
        __builtin_amdgcn_s_setprio(1);
#pragma unroll
        for (int m = 0; m < 2; ++m)
#pragma unroll
            for (int n = 0; n < 2; ++n)
                acc[m][n] = __builtin_amdgcn_mfma_f32_16x16x32_bf16(af[m], bfr[n], acc[m][n], 0, 0, 0);
        __builtin_amdgcn_s_setprio(0);
    }
    __syncthreads();
    float* red = (float*)sm;   // [64][68] padded
    if (grp == 1) {
#pragma unroll
        for (int m = 0; m < 2; ++m)
#pragma unroll
            for (int n = 0; n < 2; ++n)
#pragma unroll
                for (int j = 0; j < 4; ++j)
                    red[(wr * 32 + m * 16 + kg * 4 + j) * 68 + wc * 32 + n * 16 + cl] = acc[m][n][j];
    }
    __syncthreads();
    if (grp == 0) {
#pragma unroll
        for (int m = 0; m < 2; ++m)
#pragma unroll
            for (int n = 0; n < 2; ++n)
#pragma unroll
                for (int j = 0; j < 4; ++j) {
                    int rl = wr * 32 + m * 16 + kg * 4 + j, cll = wc * 32 + n * 16 + cl;
                    float v = acc[m][n][j] + red[rl * 68 + cll];
                    int R = br * 64 + rl, C = bc * 64 + cll;
                    *(unsigned short*)((char*)Mt + swz8_byte(R, C)) = f2bf(v);
                }
    }
}

// ---- Kernel C: streaming — h2 + Term2 + c; casts gAB -> gABh in NEW 8-chunk swizzle ----
__global__ __launch_bounds__(256) void stream_kernel(const float* __restrict__ gAB,
                                                     const float* __restrict__ sAB,
                                                     const float* __restrict__ sAG,
                                                     const float* __restrict__ ws_f,
                                                     unsigned short* __restrict__ gABh,
                                                     float* __restrict__ out,
                                                     int writecast) {
    int wave = threadIdx.x >> 6, lane = threadIdx.x & 63;
    int row = blockIdx.x * 4 + wave;
    const float* ga = gAB + (size_t)row * DIN;
    const float* sa = sAB + (size_t)row * DIN;
    const float* sg = sAG + (size_t)row * DIN;
    char* gh = (char*)gABh + (size_t)row * DIN * 2;
    int fr8 = row & 7;
    float acc = 0.f;
#pragma unroll
    for (int cc = 0; cc < 4; ++cc) {
        int col = cc * 256 + lane * 4;
        float4 a = *reinterpret_cast<const float4*>(ga + col);
        float4 x = *reinterpret_cast<const float4*>(sa + col);
        float4 y = *reinterpret_cast<const float4*>(sg + col);
        float4 v = *reinterpret_cast<const float4*>(ws_f + col);   // vab
        acc += x.x * y.x + x.y * y.y + x.z * y.z + x.w * y.w;
        acc += a.x * v.x + a.y * v.y + a.z * v.z + a.w * v.w;
        if (writecast) {
            ushort4 h; h.x = f2bf(a.x); h.y = f2bf(a.y); h.z = f2bf(a.z); h.w = f2bf(a.w);
            *reinterpret_cast<ushort4*>(gh + (col & ~63) * 2 + ((((col >> 3) & 7) ^ fr8) << 4) + (col & 7) * 2) = h;
        }
    }
#pragma unroll
    for (int off = 32; off; off >>= 1) acc += __shfl_xor(acc, off);
    if (lane == 0) out[row] = 0.5f * (acc + ws_f[2048]);
}

// ---- Kernel D: 256x256 tile, BK=64, 8 waves (2x4), KSPLIT=2, grid 256 = 1 block/CU.
//      Conflict-free ds_read via 8-chunk storage swizzle; stage-after-barrier dbuf. ----
template <int PRECAST>
__global__ __launch_bounds__(512, 2) void gemm256(const float* __restrict__ gAB,
                                                  const unsigned short* __restrict__ gABh,
                                                  const float* __restrict__ gAG,
                                                  const unsigned short* __restrict__ Mt,
                                                  const float* __restrict__ ws_f,
                                                  float* __restrict__ out) {
    __shared__ unsigned short lds_a[2][256 * 64];   // 32 KB per buffer
    __shared__ unsigned short lds_b[2][256 * 64];   // total 128 KB
    constexpr int KSPLIT = 2, KLEN = DIN / KSPLIT, NSTEP = KLEN / 64;   // 8 steps
    int b = blockIdx.x;
    // XCD map: x = b&7 = XCD; same-rblk blocks (4 cblk x 2 ks) share an XCD (gABh L2 reuse)
    int x = b & 7, s = b >> 3;        // s in [0,32)
    int rblk = x + 8 * (s & 3);       // 0..31
    int rem = s >> 2;                 // 0..7
    int ks = rem & 1;
    int cblk = rem >> 1;              // 0..3
    int tid = threadIdx.x, wave = tid >> 6, lane = tid & 63;
    int wr = wave >> 2, wc = wave & 3;        // 2 (M) x 4 (N) waves
    int kg = lane >> 4, cl = lane & 15;
    int row0 = rblk * 256, col0 = cblk * 256;

    const char* Ab = (const char*)gABh + (size_t)row0 * DIN * 2 + (size_t)(ks * KLEN) * 2;
    const char* Bb = (const char*)Mt + (size_t)col0 * DIN * 2 + (size_t)(ks * KLEN) * 2;
    const float* Af = gAB + (size_t)row0 * DIN + ks * KLEN;

    f32x4 acc[8][4] = {};

    // ---- staging helpers (per step: A 32KB + B 32KB; 2048 16B-units each, 4/thread) ----
#define STAGE_B(buf, t)                                                                   \
    _Pragma("unroll")                                                                     \
    for (int it = 0; it < 4; ++it) {                                                      \
        int u = tid + it * 512;                                                           \
        gload_lds16(Bb + (size_t)(u >> 3) * (DIN * 2) + (u & 7) * 16 + (t) * 128,         \
                    (char*)&lds_b[buf][0] + u * 16);                                      \
    }
#define STAGE_A_PRE(buf, t)                                                               \
    _Pragma("unroll")                                                                     \
    for (int it = 0; it < 4; ++it) {                                                      \
        int u = tid + it * 512;                                                           \
        gload_lds16(Ab + (size_t)(u >> 3) * (DIN * 2) + (u & 7) * 16 + (t) * 128,         \
                    (char*)&lds_a[buf][0] + u * 16);                                      \
    }
    // fallback A-staging: fp32 load + cvt + swizzled ds_write (8 f4-units/thread)
#define STAGE_A_F32(buf, t)                                                               \
    _Pragma("unroll")                                                                     \
    for (int it = 0; it < 8; ++it) {                                                      \
        int u = tid + it * 512;                     /* 0..4095 */                         \
        int row = u >> 4, c4 = u & 15;              /* col = c4*4 in [0,64) */            \
        float4 w = *reinterpret_cast<const float4*>(Af + (size_t)row * DIN + (t) * 64 + c4 * 4); \
        ushort4 h; h.x = f2bf(w.x); h.y = f2bf(w.y); h.z = f2bf(w.z); h.w = f2bf(w.w);    \
        *reinterpret_cast<ushort4*>((char*)&lds_a[buf][0] + row * 128 +                   \
                                    (((c4 >> 1) ^ (row & 7)) << 4) + (c4 & 1) * 8) = h;   \
    }

    // prologue: stage tile 0 into buf 0
    if (PRECAST) { STAGE_A_PRE(0, 0); } else { STAGE_A_F32(0, 0); }
    STAGE_B(0, 0);

    for (int t = 0; t < NSTEP; ++t) {
        int p = t & 1;
        __syncthreads();    // drains tile-t loads (t+1 not yet staged)
        if (t < NSTEP - 1) {
            if (PRECAST) { STAGE_A_PRE(p ^ 1, t + 1); } else { STAGE_A_F32(p ^ 1, t + 1); }
            STAGE_B(p ^ 1, t + 1);
        }
#pragma unroll
        for (int kk = 0; kk < 2; ++kk) {
            bf16x8 bfr[4];
#pragma unroll
            for (int n = 0; n < 4; ++n) {
                int row = wc * 64 + n * 16 + cl;
                bfr[n] = *reinterpret_cast<const bf16x8*>(&lds_b[p][row * 64 + ((((kk << 2) | kg) ^ (row & 7)) << 3)]);
            }
            bf16x8 af[8];
#pragma unroll
            for (int m = 0; m < 8; ++m) {
                int row = wr * 128 + m * 16 + cl;
                af[m] = *reinterpret_cast<const bf16x8*>(&lds_a[p][row * 64 + ((((kk << 2) | kg) ^ (row & 7)) << 3)]);
            }
            __builtin_amdgcn_s_setprio(1);
#pragma unroll
            for (int m = 0; m < 8; ++m)
#pragma unroll
                for (int n = 0; n < 4; ++n)
                    acc[m][n] = __builtin_amdgcn_mfma_f32_16x16x32_bf16(af[m], bfr[n], acc[m][n], 0, 0, 0);
            __builtin_amdgcn_s_setprio(0);
        }
    }

    // epilogue: Term1 (all ks) + Term3 (ks==0 only); gAG kept fp32
    const float* vag = ws_f + 1024;
#pragma unroll
    for (int m = 0; m < 8; ++m)
#pragma unroll
        for (int j = 0; j < 4; ++j) {
            int row = row0 + wr * 128 + m * 16 + kg * 4 + j;
            const float* gr = gAG + (size_t)row * DIN;
            float t = 0.f;
#pragma unroll
            for (int n = 0; n < 4; ++n) {
                int col = col0 + wc * 64 + n * 16 + cl;
                float addv = (ks == 0) ? vag[col] : 0.f;
                t += gr[col] * (acc[m][n][j] + addv);
            }
            t += __shfl_xor(t, 1);
            t += __shfl_xor(t, 2);
            t += __shfl_xor(t, 4);
            t += __shfl_xor(t, 8);
            if (cl == 0) atomicAdd(out + row, 0.5f * t);
        }
#undef STAGE_B
#undef STAGE_A_PRE
#undef STAGE_A_F32
}

extern "C" void kernel_launch(void* const* d_in, const int* in_sizes, int n_in,
                              void* d_out, int out_size, void* d_ws, size_t ws_size,
                              hipStream_t stream) {
    const float* gAB = (const float*)d_in[0];
    const float* gAG = (const float*)d_in[1];
    const float* Wab = (const float*)d_in[2];
    const float* Wag = (const float*)d_in[3];
    const float* bab = (const float*)d_in[4];
    const float* bag = (const float*)d_in[5];
    const float* sAB = (const float*)d_in[6];
    const float* sAG = (const float*)d_in[7];
    float* out = (float*)d_out;

    // ws layout: ws_f 16KB | Mt 2MB | Whag 2MB | Whab 2MB | gABh 16MB
    float* ws_f = (float*)d_ws;
    char* base = (char*)d_ws + 16384;
    unsigned short* Mt = (unsigned short*)base;
    unsigned short* Whag = (unsigned short*)(base + (size_t)2 * 1024 * 1024);
    unsigned short* Whab = (unsigned short*)(base + (size_t)4 * 1024 * 1024);
    unsigned short* gABh = (unsigned short*)(base + (size_t)6 * 1024 * 1024);
    size_t need_full = 16384 + (size_t)22 * 1024 * 1024;
    int precast = (ws_size >= need_full) ? 1 : 0;

    prep_kernel<<<257, 256, 0, stream>>>(Wab, Wag, bab, bag, ws_f, Whab, Whag);
    mt_kernel<<<256, 512, 0, stream>>>(Whag, Whab, Mt);
    stream_kernel<<<2048, 256, 0, stream>>>(gAB, sAB, sAG, ws_f, gABh, out, precast);
    if (precast)
        gemm256<1><<<256, 512, 0, stream>>>(gAB, gABh, gAG, Mt, ws_f, out);
    else
        gemm256<0><<<256, 512, 0, stream>>>(gAB, gABh, gAG, Mt, ws_f, out);
}